// Round 1
// baseline (555.801 us; speedup 1.0000x reference)
//
#include <hip/hip_runtime.h>

// RNN: B=256, T=512, I=256, H=128, O=1000, fp32.
// ws layout: xp[131072][128] fp32 = 64 MiB at offset 0.
//   After the recurrence, h_last[r][:] is written over xp[r*512 + 0][:]
//   (each block's own territory, already consumed at t=0).

#define HID   128
#define TSTEPS 512
#define BATCH 256
#define INDIM 256
#define ODIM  1000

// ---------------- Kernel 1: xp = x @ W_ih^T + (b_ih + b_hh) ----------------
// M=131072 (b*t), N=128, K=256. Block: 128 M-rows, all 128 N, K-chunks of 64.
// LDS transposed [k][m] / [k][n] with +1 pad. 8x8 register tile per thread.
__global__ __launch_bounds__(256) void k_phase1(const float* __restrict__ x,
                                                const float* __restrict__ Wih,
                                                const float* __restrict__ bih,
                                                const float* __restrict__ bhh,
                                                float* __restrict__ xp) {
    __shared__ float xs[64][129];   // [k][m]
    __shared__ float wsm[64][129];  // [k][n]
    __shared__ float bias_s[128];

    const int tid = threadIdx.x;
    if (tid < 128) bias_s[tid] = bih[tid] + bhh[tid];

    const int m0 = blockIdx.x * 128;
    const int tm = tid >> 4;   // 0..15 -> 8 rows each
    const int tn = tid & 15;   // 0..15 -> cols {tn*4..+3} and {64+tn*4..+3}

    float acc[8][8];
#pragma unroll
    for (int i = 0; i < 8; i++)
#pragma unroll
        for (int j = 0; j < 8; j++) acc[i][j] = 0.f;

    for (int kc = 0; kc < INDIM; kc += 64) {
        __syncthreads();
        // stage x[m0..m0+127][kc..kc+63] -> xs[k][m]; Wih[0..127][kc..kc+63] -> wsm[k][n]
#pragma unroll
        for (int q = 0; q < 8; q++) {
            int li  = q * 1024 + tid * 4;  // float index in [128 rows][64 cols] tile
            int row = li >> 6;
            int col = li & 63;
            float4 gx = *(const float4*)(x + (size_t)(m0 + row) * INDIM + kc + col);
            xs[col + 0][row] = gx.x; xs[col + 1][row] = gx.y;
            xs[col + 2][row] = gx.z; xs[col + 3][row] = gx.w;
            float4 gw = *(const float4*)(Wih + (size_t)row * INDIM + kc + col);
            wsm[col + 0][row] = gw.x; wsm[col + 1][row] = gw.y;
            wsm[col + 2][row] = gw.z; wsm[col + 3][row] = gw.w;
        }
        __syncthreads();
#pragma unroll 4
        for (int k = 0; k < 64; k++) {
            float a[8], b[8];
            *(float4*)&a[0] = *(const float4*)&xs[k][tm * 8];
            *(float4*)&a[4] = *(const float4*)&xs[k][tm * 8 + 4];
            *(float4*)&b[0] = *(const float4*)&wsm[k][tn * 4];
            *(float4*)&b[4] = *(const float4*)&wsm[k][64 + tn * 4];
#pragma unroll
            for (int i = 0; i < 8; i++)
#pragma unroll
                for (int j = 0; j < 8; j++) acc[i][j] += a[i] * b[j];
        }
    }

    float4 bia0 = *(const float4*)&bias_s[tn * 4];
    float4 bia1 = *(const float4*)&bias_s[64 + tn * 4];
#pragma unroll
    for (int i = 0; i < 8; i++) {
        int m = m0 + tm * 8 + i;
        float4 o0, o1;
        o0.x = acc[i][0] + bia0.x; o0.y = acc[i][1] + bia0.y;
        o0.z = acc[i][2] + bia0.z; o0.w = acc[i][3] + bia0.w;
        o1.x = acc[i][4] + bia1.x; o1.y = acc[i][5] + bia1.y;
        o1.z = acc[i][6] + bia1.z; o1.w = acc[i][7] + bia1.w;
        *(float4*)(xp + (size_t)m * HID + tn * 4)      = o0;
        *(float4*)(xp + (size_t)m * HID + 64 + tn * 4) = o1;
    }
}

// ---------------- Kernel 2: recurrence --------------------------------------
// One batch row per block. 256 threads: j = tid&127 (output), kh = tid>>7
// (k-half, wave-uniform). W_hh row half in VGPRs; h broadcast from LDS.
__global__ __launch_bounds__(256) void k_rnn(const float* __restrict__ Whh,
                                             float* __restrict__ ws) {
    __shared__ float h[HID];
    __shared__ float partial[HID];

    const int tid = threadIdx.x;
    const int j   = tid & 127;
    const int kh  = tid >> 7;   // 0 for waves 0-1, 1 for waves 2-3
    const int r   = blockIdx.x; // batch row

    // W_hh[j][kh*64 .. kh*64+63] into registers
    float w[64];
    const float* wrow = Whh + (size_t)j * HID + kh * 64;
#pragma unroll
    for (int q = 0; q < 16; q++)
        *(float4*)&w[q * 4] = *(const float4*)(wrow + q * 4);

    if (tid < HID) h[tid] = 0.f;

    const float* xprow = ws + (size_t)r * (TSTEPS * HID);  // xp[r][t][j]
    float xq = (kh == 0) ? xprow[j] : 0.f;                 // t=0 preload
    __syncthreads();

    for (int t = 0; t < TSTEPS; t++) {
        // prefetch next step's xp (hidden behind LDS reads + FMAs)
        float xq_next = (kh == 0 && t + 1 < TSTEPS) ? xprow[(t + 1) * HID + j] : 0.f;

        float acc = 0.f;
#pragma unroll
        for (int q = 0; q < 16; q++) {
            float4 hv = *(const float4*)&h[kh * 64 + q * 4];  // wave-uniform broadcast
            acc += hv.x * w[q * 4] + hv.y * w[q * 4 + 1]
                 + hv.z * w[q * 4 + 2] + hv.w * w[q * 4 + 3];
        }
        if (kh) partial[j] = acc;
        __syncthreads();
        if (!kh) {
            float v = acc + partial[j] + xq;
            v = fminf(fmaxf(v, -15.f), 15.f);      // tanh(±15)=±1 to fp32
            float e = __expf(2.f * v);
            h[j] = (e - 1.f) / (e + 1.f);
        }
        __syncthreads();
        xq = xq_next;
    }

    // stash h_last over this block's own xp[r][0][:]
    if (tid < HID) ws[(size_t)r * (TSTEPS * HID) + tid] = h[tid];
}

// ---------------- Kernel 3: out = h_last @ W_fc^T + b_fc --------------------
__global__ __launch_bounds__(256) void k_fc(const float* __restrict__ ws,
                                            const float* __restrict__ Wfc,
                                            const float* __restrict__ bfc,
                                            float* __restrict__ out) {
    __shared__ float hb[HID];
    const int b   = blockIdx.x;
    const int tid = threadIdx.x;
    if (tid < HID) hb[tid] = ws[(size_t)b * (TSTEPS * HID) + tid];
    __syncthreads();

    for (int o = tid; o < ODIM; o += 256) {
        const float* wr = Wfc + (size_t)o * HID;
        float acc = 0.f;
#pragma unroll
        for (int q = 0; q < 32; q++) {
            float4 wv = *(const float4*)(wr + q * 4);
            float4 hv = *(const float4*)&hb[q * 4];
            acc += wv.x * hv.x + wv.y * hv.y + wv.z * hv.z + wv.w * hv.w;
        }
        out[(size_t)b * ODIM + o] = acc + bfc[o];
    }
}

extern "C" void kernel_launch(void* const* d_in, const int* in_sizes, int n_in,
                              void* d_out, int out_size, void* d_ws, size_t ws_size,
                              hipStream_t stream) {
    const float* x   = (const float*)d_in[0];
    const float* Wih = (const float*)d_in[1];
    const float* Whh = (const float*)d_in[2];
    const float* bih = (const float*)d_in[3];
    const float* bhh = (const float*)d_in[4];
    const float* Wfc = (const float*)d_in[5];
    const float* bfc = (const float*)d_in[6];
    float* out = (float*)d_out;
    float* ws  = (float*)d_ws;   // needs 64 MiB for xp

    k_phase1<<<dim3(131072 / 128), dim3(256), 0, stream>>>(x, Wih, bih, bhh, ws);
    k_rnn   <<<dim3(BATCH),        dim3(256), 0, stream>>>(Whh, ws);
    k_fc    <<<dim3(BATCH),        dim3(256), 0, stream>>>(ws, Wfc, bfc, out);
}

// Round 2
// 477.033 us; speedup vs baseline: 1.1651x; 1.1651x over previous
//
#include <hip/hip_runtime.h>

// RNN: B=256, T=512, I=256, H=128, O=1000, fp32.
// ws: xp[131072][128] fp32 = 64 MiB. h_last[r] overwrites xp[r*512+0][:] at the end
// of the recurrence (each block's own rows, consumed at t=0 long before).

#define HID    128
#define TSTEPS 512
#define BATCH  256
#define INDIM  256
#define ODIM   1000

typedef __attribute__((ext_vector_type(8))) short bf16x8;
typedef __attribute__((ext_vector_type(4))) float f32x4;

__device__ __forceinline__ unsigned fb(float f) { return __float_as_uint(f); }
__device__ __forceinline__ float    bf(unsigned u) { return __uint_as_float(u); }
// pack hi16 of two fp32 bit-patterns: e0 -> low half, e1 -> high half
__device__ __forceinline__ unsigned hipair(unsigned e0, unsigned e1) {
    return __builtin_amdgcn_perm(e1, e0, 0x07060302u);
}
// RNE round fp32 bits to bf16 (kept in high 16 bits)
__device__ __forceinline__ unsigned rne(unsigned u) {
    return u + 0x7FFFu + ((u >> 16) & 1u);
}
__device__ __forceinline__ float tanh_fast(float p) {
    float v = fminf(fmaxf(p, -15.f), 15.f);
    float e = __expf(2.f * v);
    return 1.f - 2.f * __builtin_amdgcn_rcpf(e + 1.f);
}

// ---------------- Kernel 1: xp = x @ W_ih^T + (b_ih + b_hh) ----------------
// MFMA 16x16x32 bf16. x: RNE bf16. W_ih: hi+lo split (2 products). No LDS.
// Block: 128M x 128N; wave (wm,wn) does 64x64 as 4x4 tiles of 16x16. K=256 in 8 chunks.
__global__ __launch_bounds__(256) void k_phase1(const float* __restrict__ x,
                                                const float* __restrict__ Wih,
                                                const float* __restrict__ bih,
                                                const float* __restrict__ bhh,
                                                float* __restrict__ xp) {
    const int tid  = threadIdx.x;
    const int wave = tid >> 6, lane = tid & 63;
    const int quad = lane >> 4, l16 = lane & 15;
    const int wm = wave >> 1, wn = wave & 1;
    const int m0 = blockIdx.x * 128 + wm * 64;
    const int n0 = wn * 64;

    float bias_v[4];
#pragma unroll
    for (int nt = 0; nt < 4; nt++) {
        int j = n0 + nt * 16 + l16;
        bias_v[nt] = bih[j] + bhh[j];
    }

    f32x4 acc[4][4];
#pragma unroll
    for (int mt = 0; mt < 4; mt++)
#pragma unroll
        for (int nt = 0; nt < 4; nt++) { acc[mt][nt].x = 0.f; acc[mt][nt].y = 0.f; acc[mt][nt].z = 0.f; acc[mt][nt].w = 0.f; }

    for (int kc = 0; kc < 8; kc++) {
        const int k0 = kc * 32 + quad * 8;
        // A frags: x[m0+mt*16+l16][k0..k0+8), RNE bf16
        bf16x8 a[4];
#pragma unroll
        for (int mt = 0; mt < 4; mt++) {
            const float* p = x + (size_t)(m0 + mt * 16 + l16) * INDIM + k0;
            float4 f0 = *(const float4*)p, f1 = *(const float4*)(p + 4);
            union { unsigned u[4]; bf16x8 v; } tu;
            tu.u[0] = hipair(rne(fb(f0.x)), rne(fb(f0.y)));
            tu.u[1] = hipair(rne(fb(f0.z)), rne(fb(f0.w)));
            tu.u[2] = hipair(rne(fb(f1.x)), rne(fb(f1.y)));
            tu.u[3] = hipair(rne(fb(f1.z)), rne(fb(f1.w)));
            a[mt] = tu.v;
        }
        // B frags: Wih[n0+nt*16+l16][k0..k0+8), hi (trunc) + lo (exact residual, trunc)
        bf16x8 bhv[4], blv[4];
#pragma unroll
        for (int nt = 0; nt < 4; nt++) {
            const float* p = Wih + (size_t)(n0 + nt * 16 + l16) * INDIM + k0;
            float e[8];
            *(float4*)&e[0] = *(const float4*)p;
            *(float4*)&e[4] = *(const float4*)(p + 4);
            unsigned hu[8], lu[8];
#pragma unroll
            for (int i = 0; i < 8; i++) {
                unsigned u = fb(e[i]), hm = u & 0xFFFF0000u;
                hu[i] = hm;
                lu[i] = fb(e[i] - bf(hm));
            }
            union { unsigned u[4]; bf16x8 v; } th, tl;
#pragma unroll
            for (int q = 0; q < 4; q++) {
                th.u[q] = hipair(hu[2 * q], hu[2 * q + 1]);
                tl.u[q] = hipair(lu[2 * q], lu[2 * q + 1]);
            }
            bhv[nt] = th.v; blv[nt] = tl.v;
        }
#pragma unroll
        for (int mt = 0; mt < 4; mt++)
#pragma unroll
            for (int nt = 0; nt < 4; nt++) {
                acc[mt][nt] = __builtin_amdgcn_mfma_f32_16x16x32_bf16(a[mt], bhv[nt], acc[mt][nt], 0, 0, 0);
                acc[mt][nt] = __builtin_amdgcn_mfma_f32_16x16x32_bf16(a[mt], blv[nt], acc[mt][nt], 0, 0, 0);
            }
    }
    // store: C elem (reg) -> row = quad*4+reg, col = l16
#pragma unroll
    for (int mt = 0; mt < 4; mt++)
#pragma unroll
        for (int nt = 0; nt < 4; nt++)
#pragma unroll
            for (int reg = 0; reg < 4; reg++) {
                int row = m0 + mt * 16 + quad * 4 + reg;
                xp[(size_t)row * HID + n0 + nt * 16 + l16] = acc[mt][nt][reg] + bias_v[nt];
            }
}

// ---------------- Kernel 2: recurrence (MFMA) -------------------------------
// 16 blocks x 256 thr (4 waves). Block b: rows [16b,16b+16). Wave w: j in [32w,32w+32).
// W_hh hi/lo persistent in VGPRs (B-frags). h stored single bf16 (RNE) in LDS,
// double-buffered planes, one barrier/step. A-frags read directly as b128.
#define HROW 136  // bf16 elems per LDS h row (128 + 8 pad; 272B = 16*17, 16B-aligned, 2-way max conflicts)

#define RNN_STEP(TV, XQI, XQC, PB) {                                              \
    _Pragma("unroll") for (int jt = 0; jt < 2; jt++) {                            \
        _Pragma("unroll") for (int reg = 0; reg < 4; reg++) {                     \
            float hv = tanh_fast(C[jt][reg]);                                     \
            unsigned u = rne(fb(hv));                                             \
            hp[PB][quad * 4 + reg][wave * 32 + jt * 16 + l16] =                   \
                (unsigned short)(u >> 16);                                        \
        }                                                                         \
    }                                                                             \
    if ((TV) + 4 < TSTEPS) {                                                      \
        _Pragma("unroll") for (int jt = 0; jt < 2; jt++)                          \
            _Pragma("unroll") for (int reg = 0; reg < 4; reg++)                   \
                XQI[jt][reg] = xpb[ib[jt][reg] + ((TV) + 4) * HID];               \
    }                                                                             \
    __syncthreads();                                                              \
    bf16x8 A[4];                                                                  \
    _Pragma("unroll") for (int kc = 0; kc < 4; kc++)                              \
        A[kc] = *(const bf16x8*)&hp[PB][l16][kc * 32 + quad * 8];                 \
    _Pragma("unroll") for (int jt = 0; jt < 2; jt++) {                            \
        f32x4 c;                                                                  \
        c.x = XQC[jt][0]; c.y = XQC[jt][1]; c.z = XQC[jt][2]; c.w = XQC[jt][3];   \
        _Pragma("unroll") for (int kc = 0; kc < 4; kc++) {                        \
            c = __builtin_amdgcn_mfma_f32_16x16x32_bf16(A[kc], Bh[jt][kc], c, 0, 0, 0); \
            c = __builtin_amdgcn_mfma_f32_16x16x32_bf16(A[kc], Bl[jt][kc], c, 0, 0, 0); \
        }                                                                         \
        C[jt] = c;                                                                \
    }                                                                             \
}

__global__ __launch_bounds__(256) void k_rnn2(const float* __restrict__ Whh,
                                              float* __restrict__ ws) {
    __shared__ __align__(16) unsigned short hp[2][16][HROW];
    const int tid  = threadIdx.x;
    const int wave = tid >> 6, lane = tid & 63;
    const int quad = lane >> 4, l16 = lane & 15;
    const int r0   = blockIdx.x * 16;

    // W_hh B-frags: j = wave*32 + jt*16 + l16 (n), k = kc*32 + quad*8 + i
    bf16x8 Bh[2][4], Bl[2][4];
#pragma unroll
    for (int jt = 0; jt < 2; jt++)
#pragma unroll
        for (int kc = 0; kc < 4; kc++) {
            const float* p = Whh + (size_t)(wave * 32 + jt * 16 + l16) * HID + kc * 32 + quad * 8;
            float e[8];
            *(float4*)&e[0] = *(const float4*)p;
            *(float4*)&e[4] = *(const float4*)(p + 4);
            unsigned hu[8], lu[8];
#pragma unroll
            for (int i = 0; i < 8; i++) {
                unsigned u = fb(e[i]), hm = u & 0xFFFF0000u;
                hu[i] = hm;
                lu[i] = fb(e[i] - bf(hm));
            }
            union { unsigned u[4]; bf16x8 v; } th, tl;
#pragma unroll
            for (int q = 0; q < 4; q++) {
                th.u[q] = hipair(hu[2 * q], hu[2 * q + 1]);
                tl.u[q] = hipair(lu[2 * q], lu[2 * q + 1]);
            }
            Bh[jt][kc] = th.v; Bl[jt][kc] = tl.v;
        }

    // xp element (jt,reg) at time t: ws[(r0+quad*4+reg)*65536 + t*128 + wave*32+jt*16+l16]
    const float* xpb = ws;
    int ib[2][4];
#pragma unroll
    for (int jt = 0; jt < 2; jt++)
#pragma unroll
        for (int reg = 0; reg < 4; reg++)
            ib[jt][reg] = (r0 + quad * 4 + reg) * (TSTEPS * HID) + wave * 32 + jt * 16 + l16;

    // C init = xp_0 (h_{-1} = 0); prefetch xp_1..3
    f32x4 C[2];
    float xq0[2][4], xq1[2][4], xq2[2][4], xq3[2][4];
#pragma unroll
    for (int jt = 0; jt < 2; jt++) {
        f32x4 c;
        c.x = xpb[ib[jt][0]]; c.y = xpb[ib[jt][1]];
        c.z = xpb[ib[jt][2]]; c.w = xpb[ib[jt][3]];
        C[jt] = c;
    }
#pragma unroll
    for (int jt = 0; jt < 2; jt++)
#pragma unroll
        for (int reg = 0; reg < 4; reg++) {
            xq1[jt][reg] = xpb[ib[jt][reg] + 1 * HID];
            xq2[jt][reg] = xpb[ib[jt][reg] + 2 * HID];
            xq3[jt][reg] = xpb[ib[jt][reg] + 3 * HID];
        }

    for (int t = 0; t < 508; t += 4) {
        RNN_STEP(t,     xq0, xq1, 0);
        RNN_STEP(t + 1, xq1, xq2, 1);
        RNN_STEP(t + 2, xq2, xq3, 0);
        RNN_STEP(t + 3, xq3, xq0, 1);
    }
    RNN_STEP(508, xq0, xq1, 0);
    RNN_STEP(509, xq1, xq2, 1);
    RNN_STEP(510, xq2, xq3, 0);

    // final h_511 -> stash fp32 over xp[r][0][:] (this block's own rows)
#pragma unroll
    for (int jt = 0; jt < 2; jt++)
#pragma unroll
        for (int reg = 0; reg < 4; reg++)
            ws[ib[jt][reg]] = tanh_fast(C[jt][reg]);
}

// ---------------- Kernel 3: out = h_last @ W_fc^T + b_fc --------------------
__global__ __launch_bounds__(256) void k_fc(const float* __restrict__ ws,
                                            const float* __restrict__ Wfc,
                                            const float* __restrict__ bfc,
                                            float* __restrict__ out) {
    __shared__ float hb[HID];
    const int b   = blockIdx.x;
    const int tid = threadIdx.x;
    if (tid < HID) hb[tid] = ws[(size_t)b * (TSTEPS * HID) + tid];
    __syncthreads();

    for (int o = tid; o < ODIM; o += 256) {
        const float* wr = Wfc + (size_t)o * HID;
        float acc = 0.f;
#pragma unroll
        for (int q = 0; q < 32; q++) {
            float4 wv = *(const float4*)(wr + q * 4);
            float4 hv = *(const float4*)&hb[q * 4];
            acc += wv.x * hv.x + wv.y * hv.y + wv.z * hv.z + wv.w * hv.w;
        }
        out[(size_t)b * ODIM + o] = acc + bfc[o];
    }
}

extern "C" void kernel_launch(void* const* d_in, const int* in_sizes, int n_in,
                              void* d_out, int out_size, void* d_ws, size_t ws_size,
                              hipStream_t stream) {
    const float* x   = (const float*)d_in[0];
    const float* Wih = (const float*)d_in[1];
    const float* Whh = (const float*)d_in[2];
    const float* bih = (const float*)d_in[3];
    const float* bhh = (const float*)d_in[4];
    const float* Wfc = (const float*)d_in[5];
    const float* bfc = (const float*)d_in[6];
    float* out = (float*)d_out;
    float* ws  = (float*)d_ws;  // 64 MiB xp

    k_phase1<<<dim3(1024), dim3(256), 0, stream>>>(x, Wih, bih, bhh, ws);
    k_rnn2  <<<dim3(16),   dim3(256), 0, stream>>>(Whh, ws);
    k_fc    <<<dim3(BATCH), dim3(256), 0, stream>>>(ws, Wfc, bfc, out);
}

// Round 3
// 424.324 us; speedup vs baseline: 1.3098x; 1.1242x over previous
//
#include <hip/hip_runtime.h>

// RNN: B=256, T=512, I=256, H=128, O=1000, fp32.
// ws: xp[131072][128] fp32 = 64 MiB. h_last[r] overwrites xp[r*512+0][:] after the
// recurrence (each block's own rows, consumed at t=0 long before).

#define HID    128
#define TSTEPS 512
#define BATCH  256
#define INDIM  256
#define ODIM   1000

typedef __attribute__((ext_vector_type(8))) short bf16x8;
typedef __attribute__((ext_vector_type(4))) float f32x4;

__device__ __forceinline__ unsigned fb(float f) { return __float_as_uint(f); }
__device__ __forceinline__ float    bf(unsigned u) { return __uint_as_float(u); }
// pack hi16 of two fp32 bit-patterns: e0 -> low half, e1 -> high half
__device__ __forceinline__ unsigned hipair(unsigned e0, unsigned e1) {
    return __builtin_amdgcn_perm(e1, e0, 0x07060302u);
}
// RNE round fp32 bits to bf16 (kept in high 16 bits)
__device__ __forceinline__ unsigned rne(unsigned u) {
    return u + 0x7FFFu + ((u >> 16) & 1u);
}
__device__ __forceinline__ float tanh_fast(float p) {
    float v = fminf(fmaxf(p, -15.f), 15.f);
    float e = __expf(2.f * v);
    return 1.f - 2.f * __builtin_amdgcn_rcpf(e + 1.f);
}

// ---------------- Kernel 1: xp = x @ W_ih^T + (b_ih + b_hh) ----------------
// MFMA 16x16x32 bf16, m97-style double-buffered LDS staging with bf16 conversion
// at stage time. LDS rows are 32 elems (64B) = four 16B chunks, XOR-swizzled
// chunk c -> c ^ (row&3) so frag b128 reads are conflict-free.
__global__ __launch_bounds__(256) void k_phase1(const float* __restrict__ x,
                                                const float* __restrict__ Wih,
                                                const float* __restrict__ bih,
                                                const float* __restrict__ bhh,
                                                float* __restrict__ xp) {
    __shared__ __align__(16) unsigned short xs[2][4096];   // x tile, bf16
    __shared__ __align__(16) unsigned short whs[2][4096];  // W hi
    __shared__ __align__(16) unsigned short wls[2][4096];  // W lo

    const int tid  = threadIdx.x;
    const int wave = tid >> 6, lane = tid & 63;
    const int quad = lane >> 4, l16 = lane & 15;
    const int wm = wave >> 1, wn = wave & 1;
    const int m0 = blockIdx.x * 128;

    // staging geometry: li = q*256+tid -> row = li>>3 (0..127), c = li&7 (8B units)
    int srow[4], scol[4], sdst[4];
#pragma unroll
    for (int q = 0; q < 4; q++) {
        int li = q * 256 + tid;
        srow[q] = li >> 3;
        scol[q] = li & 7;
        sdst[q] = srow[q] * 32 + ((((scol[q] >> 1) ^ srow[q]) & 3) << 3) + ((scol[q] & 1) << 2);
    }

    float bias_v[4];
#pragma unroll
    for (int nt = 0; nt < 4; nt++) {
        int j = wn * 64 + nt * 16 + l16;
        bias_v[nt] = bih[j] + bhh[j];
    }

    float4 rx[4], rw[4];
#define LOAD_STAGE(KC)                                                              \
    {                                                                               \
        _Pragma("unroll") for (int q = 0; q < 4; q++) {                             \
            rx[q] = *(const float4*)(x + (size_t)(m0 + srow[q]) * INDIM + (KC) * 32 + scol[q] * 4); \
            rw[q] = *(const float4*)(Wih + (size_t)srow[q] * INDIM + (KC) * 32 + scol[q] * 4);      \
        }                                                                           \
    }
#define WRITE_STAGE(BUF)                                                            \
    {                                                                               \
        _Pragma("unroll") for (int q = 0; q < 4; q++) {                             \
            uint2 px;                                                               \
            px.x = hipair(rne(fb(rx[q].x)), rne(fb(rx[q].y)));                      \
            px.y = hipair(rne(fb(rx[q].z)), rne(fb(rx[q].w)));                      \
            *(uint2*)&xs[BUF][sdst[q]] = px;                                        \
            unsigned u0 = fb(rw[q].x) & 0xFFFF0000u, u1 = fb(rw[q].y) & 0xFFFF0000u;\
            unsigned u2 = fb(rw[q].z) & 0xFFFF0000u, u3 = fb(rw[q].w) & 0xFFFF0000u;\
            unsigned v0 = fb(rw[q].x - bf(u0)), v1 = fb(rw[q].y - bf(u1));          \
            unsigned v2 = fb(rw[q].z - bf(u2)), v3 = fb(rw[q].w - bf(u3));          \
            uint2 ph, pl;                                                           \
            ph.x = hipair(u0, u1); ph.y = hipair(u2, u3);                           \
            pl.x = hipair(v0, v1); pl.y = hipair(v2, v3);                           \
            *(uint2*)&whs[BUF][sdst[q]] = ph;                                       \
            *(uint2*)&wls[BUF][sdst[q]] = pl;                                       \
        }                                                                           \
    }

    f32x4 acc[4][4];
#pragma unroll
    for (int mt = 0; mt < 4; mt++)
#pragma unroll
        for (int nt = 0; nt < 4; nt++) {
            acc[mt][nt].x = 0.f; acc[mt][nt].y = 0.f;
            acc[mt][nt].z = 0.f; acc[mt][nt].w = 0.f;
        }

    LOAD_STAGE(0);
    WRITE_STAGE(0);
    __syncthreads();

    for (int kc = 0; kc < 8; kc++) {
        const int b = kc & 1;
        if (kc < 7) LOAD_STAGE(kc + 1);

        bf16x8 a[4], bh[4], bl[4];
#pragma unroll
        for (int mt = 0; mt < 4; mt++) {
            int row = wm * 64 + mt * 16 + l16;
            a[mt] = *(const bf16x8*)&xs[b][row * 32 + (((quad ^ row) & 3) << 3)];
        }
#pragma unroll
        for (int nt = 0; nt < 4; nt++) {
            int row = wn * 64 + nt * 16 + l16;
            int ad  = row * 32 + (((quad ^ row) & 3) << 3);
            bh[nt] = *(const bf16x8*)&whs[b][ad];
            bl[nt] = *(const bf16x8*)&wls[b][ad];
        }
#pragma unroll
        for (int mt = 0; mt < 4; mt++)
#pragma unroll
            for (int nt = 0; nt < 4; nt++) {
                acc[mt][nt] = __builtin_amdgcn_mfma_f32_16x16x32_bf16(a[mt], bh[nt], acc[mt][nt], 0, 0, 0);
                acc[mt][nt] = __builtin_amdgcn_mfma_f32_16x16x32_bf16(a[mt], bl[nt], acc[mt][nt], 0, 0, 0);
            }

        if (kc < 7) WRITE_STAGE(b ^ 1);
        __syncthreads();
    }

    // C layout: col = l16, row = quad*4 + reg
#pragma unroll
    for (int mt = 0; mt < 4; mt++)
#pragma unroll
        for (int nt = 0; nt < 4; nt++)
#pragma unroll
            for (int reg = 0; reg < 4; reg++) {
                int row = m0 + wm * 64 + mt * 16 + quad * 4 + reg;
                xp[(size_t)row * HID + wn * 64 + nt * 16 + l16] = acc[mt][nt][reg] + bias_v[nt];
            }
#undef LOAD_STAGE
#undef WRITE_STAGE
}

// ---------------- Kernel 2: recurrence (MFMA, 8 waves) ----------------------
// 16 blocks x 512 thr. Block b: rows [16b,16b+16). Wave w: j in [16w,16w+16).
// W_hh hi/lo persistent in VGPRs. h in LDS as bf16, 2 planes, 1 barrier/step.
// Row = 128 bf16 = 256B = sixteen 16B chunks, XOR-swizzled c -> c ^ (m&15):
// b128 A-frag reads are 2-way max (free), b16 writes spread across banks.
#define RNN_STEP3(TV, XQI, XQC, PB) {                                             \
    _Pragma("unroll") for (int reg = 0; reg < 4; reg++) {                         \
        float hv = tanh_fast(C[reg]);                                             \
        unsigned u = rne(fb(hv));                                                 \
        int m = quad * 4 + reg;                                                   \
        hp[PB][m * 128 + ((((jbase >> 3) ^ m) & 15) << 3) + (jbase & 7)] =        \
            (unsigned short)(u >> 16);                                            \
    }                                                                             \
    if ((TV) + 4 < TSTEPS) {                                                      \
        _Pragma("unroll") for (int reg = 0; reg < 4; reg++)                       \
            XQI[reg] = xpb[ib[reg] + ((TV) + 4) * HID];                           \
    }                                                                             \
    __syncthreads();                                                              \
    bf16x8 A[4];                                                                  \
    _Pragma("unroll") for (int kc = 0; kc < 4; kc++)                              \
        A[kc] = *(const bf16x8*)&hp[PB][l16 * 128 + ((((kc * 4 + quad) ^ l16) & 15) << 3)]; \
    f32x4 ch, cl;                                                                 \
    ch.x = XQC[0]; ch.y = XQC[1]; ch.z = XQC[2]; ch.w = XQC[3];                   \
    cl.x = 0.f; cl.y = 0.f; cl.z = 0.f; cl.w = 0.f;                               \
    _Pragma("unroll") for (int kc = 0; kc < 4; kc++) {                            \
        ch = __builtin_amdgcn_mfma_f32_16x16x32_bf16(A[kc], Bh[kc], ch, 0, 0, 0); \
        cl = __builtin_amdgcn_mfma_f32_16x16x32_bf16(A[kc], Bl[kc], cl, 0, 0, 0); \
    }                                                                             \
    C = ch + cl;                                                                  \
}

__global__ __launch_bounds__(512) void k_rnn3(const float* __restrict__ Whh,
                                              float* __restrict__ ws) {
    __shared__ __align__(16) unsigned short hp[2][16 * 128];
    const int tid  = threadIdx.x;
    const int wave = tid >> 6, lane = tid & 63;
    const int quad = lane >> 4, l16 = lane & 15;
    const int r0    = blockIdx.x * 16;
    const int jbase = wave * 16 + l16;   // this thread's output j (0..127)

    // W_hh B-frags: n = jbase, k = kc*32 + quad*8 + i; hi + lo split
    bf16x8 Bh[4], Bl[4];
#pragma unroll
    for (int kc = 0; kc < 4; kc++) {
        const float* p = Whh + (size_t)jbase * HID + kc * 32 + quad * 8;
        float e[8];
        *(float4*)&e[0] = *(const float4*)p;
        *(float4*)&e[4] = *(const float4*)(p + 4);
        unsigned hu[8], lu[8];
#pragma unroll
        for (int i = 0; i < 8; i++) {
            unsigned u = fb(e[i]), hm = u & 0xFFFF0000u;
            hu[i] = hm;
            lu[i] = fb(e[i] - bf(hm));
        }
        union { unsigned u[4]; bf16x8 v; } th, tl;
#pragma unroll
        for (int q = 0; q < 4; q++) {
            th.u[q] = hipair(hu[2 * q], hu[2 * q + 1]);
            tl.u[q] = hipair(lu[2 * q], lu[2 * q + 1]);
        }
        Bh[kc] = th.v; Bl[kc] = tl.v;
    }

    const float* xpb = ws;
    int ib[4];
#pragma unroll
    for (int reg = 0; reg < 4; reg++)
        ib[reg] = (r0 + quad * 4 + reg) * (TSTEPS * HID) + jbase;

    // C init = xp_0 (h_{-1}=0); prefetch xp_1..3
    f32x4 C;
    float xq0[4], xq1[4], xq2[4], xq3[4];
    C.x = xpb[ib[0]]; C.y = xpb[ib[1]]; C.z = xpb[ib[2]]; C.w = xpb[ib[3]];
#pragma unroll
    for (int reg = 0; reg < 4; reg++) {
        xq1[reg] = xpb[ib[reg] + 1 * HID];
        xq2[reg] = xpb[ib[reg] + 2 * HID];
        xq3[reg] = xpb[ib[reg] + 3 * HID];
    }

    for (int t = 0; t < 508; t += 4) {
        RNN_STEP3(t,     xq0, xq1, 0);
        RNN_STEP3(t + 1, xq1, xq2, 1);
        RNN_STEP3(t + 2, xq2, xq3, 0);
        RNN_STEP3(t + 3, xq3, xq0, 1);
    }
    RNN_STEP3(508, xq0, xq1, 0);
    RNN_STEP3(509, xq1, xq2, 1);
    RNN_STEP3(510, xq2, xq3, 0);

    // h_511 -> stash fp32 over xp[r][0][:]
#pragma unroll
    for (int reg = 0; reg < 4; reg++)
        ws[ib[reg]] = tanh_fast(C[reg]);
}

// ---------------- Kernel 3: out = h_last @ W_fc^T + b_fc --------------------
__global__ __launch_bounds__(256) void k_fc(const float* __restrict__ ws,
                                            const float* __restrict__ Wfc,
                                            const float* __restrict__ bfc,
                                            float* __restrict__ out) {
    __shared__ float hb[HID];
    const int b   = blockIdx.x;
    const int tid = threadIdx.x;
    if (tid < HID) hb[tid] = ws[(size_t)b * (TSTEPS * HID) + tid];
    __syncthreads();

    for (int o = tid; o < ODIM; o += 256) {
        const float* wr = Wfc + (size_t)o * HID;
        float acc = 0.f;
#pragma unroll
        for (int q = 0; q < 32; q++) {
            float4 wv = *(const float4*)(wr + q * 4);
            float4 hv = *(const float4*)&hb[q * 4];
            acc += wv.x * hv.x + wv.y * hv.y + wv.z * hv.z + wv.w * hv.w;
        }
        out[(size_t)b * ODIM + o] = acc + bfc[o];
    }
}

extern "C" void kernel_launch(void* const* d_in, const int* in_sizes, int n_in,
                              void* d_out, int out_size, void* d_ws, size_t ws_size,
                              hipStream_t stream) {
    const float* x   = (const float*)d_in[0];
    const float* Wih = (const float*)d_in[1];
    const float* Whh = (const float*)d_in[2];
    const float* bih = (const float*)d_in[3];
    const float* bhh = (const float*)d_in[4];
    const float* Wfc = (const float*)d_in[5];
    const float* bfc = (const float*)d_in[6];
    float* out = (float*)d_out;
    float* ws  = (float*)d_ws;  // 64 MiB xp

    k_phase1<<<dim3(1024), dim3(256), 0, stream>>>(x, Wih, bih, bhh, ws);
    k_rnn3  <<<dim3(16),   dim3(512), 0, stream>>>(Whh, ws);
    k_fc    <<<dim3(BATCH), dim3(256), 0, stream>>>(ws, Wfc, bfc, out);
}

// Round 5
// 393.034 us; speedup vs baseline: 1.4141x; 1.0796x over previous
//
#include <hip/hip_runtime.h>

// RNN: B=256, T=512, I=256, H=128, O=1000, fp32 in/out.
// Internals in fp16 (11-bit mantissa): W,x,h at 2^-12 rel err -> absmax ~4e-3,
// threshold 3.3e-2. Single MFMA product per tile (no hi/lo split).
// ws: xp[131072][128] fp32 = 64 MiB. h_last[r] overwrites xp[r*512+0][:] after
// the recurrence (each block's own rows, consumed at t=0 long before).

#define HID    128
#define TSTEPS 512
#define BATCH  256
#define INDIM  256
#define ODIM   1000

typedef _Float16 f16x8 __attribute__((ext_vector_type(8)));
typedef __fp16   fp16x2 __attribute__((ext_vector_type(2)));
typedef float    f32x4 __attribute__((ext_vector_type(4)));

__device__ __forceinline__ unsigned pk16(float a, float b) {
    union { fp16x2 h; unsigned u; } t;
    t.h = __builtin_amdgcn_cvt_pkrtz(a, b);   // packs 2 fp32 -> 2 fp16 (RTZ)
    return t.u;
}
// tanh without clamp: exp2 overflow->inf->rcp->0 gives +1; underflow->0 gives -1.
__device__ __forceinline__ float tanh_fast(float v) {
    float e = __expf(2.f * v);                 // v_mul + v_exp_f32
    float r = __builtin_amdgcn_rcpf(e + 1.f);  // v_add + v_rcp_f32
    return __builtin_fmaf(-2.f, r, 1.f);
}

// ---------------- Kernel 1: xp = x @ W_ih^T + (b_ih + b_hh) ----------------
// MFMA 16x16x32 f16, double-buffered LDS staging, fp16 conversion at stage time.
// LDS tile rows = 32 k-elems (64B) = four 16B chunks, XOR-swizzled c ^= (row&3).
__global__ __launch_bounds__(256) void k_phase1(const float* __restrict__ x,
                                                const float* __restrict__ Wih,
                                                const float* __restrict__ bih,
                                                const float* __restrict__ bhh,
                                                float* __restrict__ xp) {
    __shared__ __align__(16) _Float16 xs[2][4096];   // x tile fp16
    __shared__ __align__(16) _Float16 wsm[2][4096];  // W tile fp16

    const int tid  = threadIdx.x;
    const int wave = tid >> 6, lane = tid & 63;
    const int quad = lane >> 4, l16 = lane & 15;
    const int wm = wave >> 1, wn = wave & 1;
    const int m0 = blockIdx.x * 128;

    // staging geometry: li = q*256+tid -> row = li>>3 (0..127), c = li&7 (4-float units)
    int srow[4], scol[4], sdst[4];
#pragma unroll
    for (int q = 0; q < 4; q++) {
        int li = q * 256 + tid;
        srow[q] = li >> 3;
        scol[q] = li & 7;
        sdst[q] = srow[q] * 32 + ((((scol[q] >> 1) ^ srow[q]) & 3) << 3) + ((scol[q] & 1) << 2);
    }

    float bias_v[4];
#pragma unroll
    for (int nt = 0; nt < 4; nt++) {
        int j = wn * 64 + nt * 16 + l16;
        bias_v[nt] = bih[j] + bhh[j];
    }

    float4 rx[4], rw[4];
#define LOAD_STAGE(KC)                                                              \
    {                                                                               \
        _Pragma("unroll") for (int q = 0; q < 4; q++) {                             \
            rx[q] = *(const float4*)(x + (size_t)(m0 + srow[q]) * INDIM + (KC) * 32 + scol[q] * 4); \
            rw[q] = *(const float4*)(Wih + (size_t)srow[q] * INDIM + (KC) * 32 + scol[q] * 4);      \
        }                                                                           \
    }
#define WRITE_STAGE(BUF)                                                            \
    {                                                                               \
        _Pragma("unroll") for (int q = 0; q < 4; q++) {                             \
            uint2 px, pw;                                                           \
            px.x = pk16(rx[q].x, rx[q].y); px.y = pk16(rx[q].z, rx[q].w);           \
            pw.x = pk16(rw[q].x, rw[q].y); pw.y = pk16(rw[q].z, rw[q].w);           \
            *(uint2*)&xs[BUF][sdst[q]]  = px;                                       \
            *(uint2*)&wsm[BUF][sdst[q]] = pw;                                       \
        }                                                                           \
    }

    f32x4 acc[4][4];
#pragma unroll
    for (int mt = 0; mt < 4; mt++)
#pragma unroll
        for (int nt = 0; nt < 4; nt++) {
            acc[mt][nt].x = 0.f; acc[mt][nt].y = 0.f;
            acc[mt][nt].z = 0.f; acc[mt][nt].w = 0.f;
        }

    LOAD_STAGE(0);
    WRITE_STAGE(0);
    __syncthreads();

    for (int kc = 0; kc < 8; kc++) {
        const int b = kc & 1;
        if (kc < 7) LOAD_STAGE(kc + 1);

        f16x8 a[4], bw[4];
#pragma unroll
        for (int mt = 0; mt < 4; mt++) {
            int row = wm * 64 + mt * 16 + l16;
            a[mt] = *(const f16x8*)&xs[b][row * 32 + (((quad ^ row) & 3) << 3)];
        }
#pragma unroll
        for (int nt = 0; nt < 4; nt++) {
            int row = wn * 64 + nt * 16 + l16;
            bw[nt] = *(const f16x8*)&wsm[b][row * 32 + (((quad ^ row) & 3) << 3)];
        }
#pragma unroll
        for (int mt = 0; mt < 4; mt++)
#pragma unroll
            for (int nt = 0; nt < 4; nt++)
                acc[mt][nt] = __builtin_amdgcn_mfma_f32_16x16x32_f16(a[mt], bw[nt], acc[mt][nt], 0, 0, 0);

        if (kc < 7) WRITE_STAGE(b ^ 1);
        __syncthreads();
    }

    // C layout: col = l16, row = quad*4 + reg
#pragma unroll
    for (int mt = 0; mt < 4; mt++)
#pragma unroll
        for (int nt = 0; nt < 4; nt++)
#pragma unroll
            for (int reg = 0; reg < 4; reg++) {
                int row = m0 + wm * 64 + mt * 16 + quad * 4 + reg;
                xp[(size_t)row * HID + wn * 64 + nt * 16 + l16] = acc[mt][nt][reg] + bias_v[nt];
            }
#undef LOAD_STAGE
#undef WRITE_STAGE
}

// ---------------- Kernel 2: recurrence (MFMA f16, 8 waves) ------------------
// 16 blocks x 512 thr. Block b: rows [16b,16b+16). Wave w: j in [16w,16w+16).
// W_hh fp16 persistent in VGPRs (16 regs). h in LDS fp16, 2 planes, 1 barrier
// per step. Row = 128 fp16 = 256B = 16 chunks of 16B, XOR-swizzled c ^= (m&15):
// b128 A-frag reads conflict-free (verified 0 conflicts round 3), b16 writes
// 2-way max (free). Two parallel MFMA chains of 2 halve chain latency.
#define RNN_STEP4(TV, XQI, XQC, PB) {                                             \
    _Pragma("unroll") for (int reg = 0; reg < 4; reg++) {                         \
        float hv = tanh_fast(C[reg]);                                             \
        int m = quad * 4 + reg;                                                   \
        hp[PB][m * 128 + ((((jbase >> 3) ^ m) & 15) << 3) + (jbase & 7)] =        \
            (_Float16)hv;                                                         \
    }                                                                             \
    if ((TV) + 4 < TSTEPS) {                                                      \
        _Pragma("unroll") for (int reg = 0; reg < 4; reg++)                       \
            XQI[reg] = xpb[ib[reg] + ((TV) + 4) * HID];                           \
    }                                                                             \
    __syncthreads();                                                              \
    f16x8 A[4];                                                                   \
    _Pragma("unroll") for (int kc = 0; kc < 4; kc++)                              \
        A[kc] = *(const f16x8*)&hp[PB][l16 * 128 + ((((kc * 4 + quad) ^ l16) & 15) << 3)]; \
    f32x4 ch, cl;                                                                 \
    ch.x = XQC[0]; ch.y = XQC[1]; ch.z = XQC[2]; ch.w = XQC[3];                   \
    cl.x = 0.f; cl.y = 0.f; cl.z = 0.f; cl.w = 0.f;                               \
    ch = __builtin_amdgcn_mfma_f32_16x16x32_f16(A[0], Bf[0], ch, 0, 0, 0);        \
    cl = __builtin_amdgcn_mfma_f32_16x16x32_f16(A[2], Bf[2], cl, 0, 0, 0);        \
    ch = __builtin_amdgcn_mfma_f32_16x16x32_f16(A[1], Bf[1], ch, 0, 0, 0);        \
    cl = __builtin_amdgcn_mfma_f32_16x16x32_f16(A[3], Bf[3], cl, 0, 0, 0);        \
    C = ch + cl;                                                                  \
}

__global__ __launch_bounds__(512) void k_rnn4(const float* __restrict__ Whh,
                                              float* __restrict__ ws) {
    __shared__ __align__(16) _Float16 hp[2][16 * 128];
    const int tid  = threadIdx.x;
    const int wave = tid >> 6, lane = tid & 63;
    const int quad = lane >> 4, l16 = lane & 15;
    const int r0    = blockIdx.x * 16;
    const int jbase = wave * 16 + l16;   // this thread's output j (0..127)

    // W_hh B-frags fp16: n = jbase, k = kc*32 + quad*8 + i
    f16x8 Bf[4];
#pragma unroll
    for (int kc = 0; kc < 4; kc++) {
        const float* p = Whh + (size_t)jbase * HID + kc * 32 + quad * 8;
        float4 e0 = *(const float4*)p, e1 = *(const float4*)(p + 4);
        union { unsigned u[4]; f16x8 v; } t;
        t.u[0] = pk16(e0.x, e0.y); t.u[1] = pk16(e0.z, e0.w);
        t.u[2] = pk16(e1.x, e1.y); t.u[3] = pk16(e1.z, e1.w);
        Bf[kc] = t.v;
    }

    const float* xpb = ws;
    int ib[4];
#pragma unroll
    for (int reg = 0; reg < 4; reg++)
        ib[reg] = (r0 + quad * 4 + reg) * (TSTEPS * HID) + jbase;

    // C init = xp_0 (h_{-1}=0); prefetch xp_1..3
    f32x4 C;
    float xq0[4], xq1[4], xq2[4], xq3[4];
    C.x = xpb[ib[0]]; C.y = xpb[ib[1]]; C.z = xpb[ib[2]]; C.w = xpb[ib[3]];
#pragma unroll
    for (int reg = 0; reg < 4; reg++) {
        xq1[reg] = xpb[ib[reg] + 1 * HID];
        xq2[reg] = xpb[ib[reg] + 2 * HID];
        xq3[reg] = xpb[ib[reg] + 3 * HID];
    }

    for (int t = 0; t < 508; t += 4) {
        RNN_STEP4(t,     xq0, xq1, 0);
        RNN_STEP4(t + 1, xq1, xq2, 1);
        RNN_STEP4(t + 2, xq2, xq3, 0);
        RNN_STEP4(t + 3, xq3, xq0, 1);
    }
    RNN_STEP4(508, xq0, xq1, 0);
    RNN_STEP4(509, xq1, xq2, 1);
    RNN_STEP4(510, xq2, xq3, 0);

    // h_511 -> stash fp32 over xp[r][0][:] (this block's own rows)
#pragma unroll
    for (int reg = 0; reg < 4; reg++)
        ws[ib[reg]] = tanh_fast(C[reg]);
}

// ---------------- Kernel 3: out = h_last @ W_fc^T + b_fc --------------------
__global__ __launch_bounds__(256) void k_fc(const float* __restrict__ ws,
                                            const float* __restrict__ Wfc,
                                            const float* __restrict__ bfc,
                                            float* __restrict__ out) {
    __shared__ float hb[HID];
    const int b   = blockIdx.x;
    const int tid = threadIdx.x;
    if (tid < HID) hb[tid] = ws[(size_t)b * (TSTEPS * HID) + tid];
    __syncthreads();

    for (int o = tid; o < ODIM; o += 256) {
        const float* wr = Wfc + (size_t)o * HID;
        float acc = 0.f;
#pragma unroll
        for (int q = 0; q < 32; q++) {
            float4 wv = *(const float4*)(wr + q * 4);
            float4 hv = *(const float4*)&hb[q * 4];
            acc += wv.x * hv.x + wv.y * hv.y + wv.z * hv.z + wv.w * hv.w;
        }
        out[(size_t)b * ODIM + o] = acc + bfc[o];
    }
}

extern "C" void kernel_launch(void* const* d_in, const int* in_sizes, int n_in,
                              void* d_out, int out_size, void* d_ws, size_t ws_size,
                              hipStream_t stream) {
    const float* x   = (const float*)d_in[0];
    const float* Wih = (const float*)d_in[1];
    const float* Whh = (const float*)d_in[2];
    const float* bih = (const float*)d_in[3];
    const float* bhh = (const float*)d_in[4];
    const float* Wfc = (const float*)d_in[5];
    const float* bfc = (const float*)d_in[6];
    float* out = (float*)d_out;
    float* ws  = (float*)d_ws;  // 64 MiB xp

    k_phase1<<<dim3(1024), dim3(256), 0, stream>>>(x, Wih, bih, bhh, ws);
    k_rnn4  <<<dim3(16),   dim3(512), 0, stream>>>(Whh, ws);
    k_fc    <<<dim3(BATCH), dim3(256), 0, stream>>>(ws, Wfc, bfc, out);
}